// Round 12
// baseline (268.074 us; speedup 1.0000x reference)
//
#include <hip/hip_runtime.h>

#define HID 128
#define LN_EPS 1e-5f

using f32x2 = __attribute__((ext_vector_type(2))) float;
using f32x4 = __attribute__((ext_vector_type(4))) float;
using s16x8 = __attribute__((ext_vector_type(8))) short;

__device__ inline float bl2f(unsigned u) { u <<= 16; return __builtin_bit_cast(float, u); }
__device__ inline float bh2f(unsigned u) { u &= 0xffff0000u; return __builtin_bit_cast(float, u); }
__device__ inline float sb2f(short s) {
  unsigned u = ((unsigned)(unsigned short)s) << 16;
  return __builtin_bit_cast(float, u);
}
__device__ inline unsigned f2b_bits(float f) {
  unsigned u = __builtin_bit_cast(unsigned, f);
  return (u + 0x7fffu + ((u >> 16) & 1u)) >> 16;  // RNE
}
__device__ inline short f2b(float f) { return (short)f2b_bits(f); }
__device__ inline unsigned pack2(float a, float b) { return f2b_bits(a) | (f2b_bits(b) << 16); }
__device__ inline f32x2 up2(unsigned u) {
  f32x2 r; r.x = bl2f(u); r.y = bh2f(u); return r;
}

// ---------------- weight prep: Wt[w][n][k] = bf16(src_w[k][n]); w=0 -> W_pre, w>=1 -> conv_W[w-1] ----------------

__global__ __launch_bounds__(64) void prep_w_kernel(const float* __restrict__ W_pre,
                                                    const float* __restrict__ conv_W,
                                                    short* __restrict__ Wt) {
  int b = blockIdx.x;            // 0..639
  int w = b >> 7, n = b & 127;
  const float* W = (w == 0) ? W_pre : conv_W + (size_t)(w - 1) * HID * HID;
  int t = threadIdx.x;           // k = 2t, 2t+1
  float f0 = W[(2 * t) * HID + n];
  float f1 = W[(2 * t + 1) * HID + n];
  ((unsigned*)Wt)[(size_t)(w * HID + n) * 64 + t] = pack2(f0, f1);
}

// ---------------- CSR build (scan-free) + degree-sort ----------------

__global__ void zero_ints_kernel(int* __restrict__ p, int n) {
  int i = blockIdx.x * blockDim.x + threadIdx.x;
  if (i < n) p[i] = 0;
}

__global__ void deg_count_kernel(const int* __restrict__ dst, int E, int* __restrict__ deg) {
  int e = blockIdx.x * blockDim.x + threadIdx.x;
  if (e < E) atomicAdd(&deg[dst[e]], 1);
}

// block scan for CSR offsets + dinv + LDS-private degree histogram (64B-padded global bins)
__global__ __launch_bounds__(256) void alloc_kernel(const int* __restrict__ deg,
                                                    int* __restrict__ start,
                                                    int* __restrict__ cur,
                                                    float* __restrict__ dinv,
                                                    int* __restrict__ cnt,
                                                    int* __restrict__ hist, int n) {
  __shared__ int wt[4];
  __shared__ int bbase;
  __shared__ int lh[64];
  int t = threadIdx.x, lane = t & 63, wid = t >> 6;
  if (t < 64) lh[t] = 0;
  int i = blockIdx.x * 256 + t;
  int d = (i < n) ? deg[i] : 0;
  int x = d;
  #pragma unroll
  for (int off = 1; off < 64; off <<= 1) {
    int u = __shfl_up(x, off, 64);
    if (lane >= off) x += u;
  }
  if (lane == 63) wt[wid] = x;
  __syncthreads();
  if (i < n) atomicAdd(&lh[min(d, 63)], 1);
  if (t == 0) bbase = atomicAdd(cnt, wt[0] + wt[1] + wt[2] + wt[3]);
  __syncthreads();
  int wbase = bbase;
  for (int w = 0; w < wid; ++w) wbase += wt[w];
  int excl = wbase + x - d;
  if (i < n) {
    start[i] = excl;
    cur[i] = excl;
    dinv[i] = rsqrtf((float)(d + 1));
  }
  if (t < 64 && lh[t]) atomicAdd(&hist[t * 16], lh[t]);
}

__global__ void fill_csr_kernel(const int* __restrict__ src, const int* __restrict__ dst,
                                int E, int* __restrict__ cur, int* __restrict__ col) {
  int e = blockIdx.x * blockDim.x + threadIdx.x;
  if (e < E) {
    int d = dst[e];
    int p = atomicAdd(&cur[d], 1);
    col[p] = src[e];
  }
}

// descending-degree bin offsets (heavy bins first so straggler blocks start early)
__global__ __launch_bounds__(64) void binoff_kernel(const int* __restrict__ hist,
                                                    int* __restrict__ bincur) {
  int lane = threadIdx.x;    // 0..63
  int rb = 63 - lane;        // bin 63 gets offset 0
  int v = hist[rb * 16];
  int x = v;
  #pragma unroll
  for (int off = 1; off < 64; off <<= 1) {
    int u = __shfl_up(x, off, 64);
    if (lane >= off) x += u;
  }
  bincur[rb * 16] = x - v;
}

// Per-block LDS ranking + one padded global atomic per bin per block.
#define SNODES 1024
__global__ __launch_bounds__(256) void scatter_kernel(const int* __restrict__ deg,
                                                      int* __restrict__ bincur,
                                                      int* __restrict__ perm, int n) {
  __shared__ int lh[64];
  __shared__ int lbase[64];
  int t = threadIdx.x;
  if (t < 64) lh[t] = 0;
  __syncthreads();
  int nstart = blockIdx.x * SNODES;
  int nend = min(n, nstart + SNODES);
  int myb[4], myrank[4];
  int cnt = 0;
  for (int i = nstart + t; i < nend; i += 256) {
    int b = min(deg[i], 63);
    myb[cnt] = b;
    myrank[cnt] = atomicAdd(&lh[b], 1);
    ++cnt;
  }
  __syncthreads();
  if (t < 64) lbase[t] = lh[t] ? atomicAdd(&bincur[t * 16], lh[t]) : 0;
  __syncthreads();
  int k = 0;
  for (int i = nstart + t; i < nend; i += 256, ++k)
    perm[lbase[myb[k]] + myrank[k]] = i;
}

// ---------------- MFMA GEMM (pre): S0 = dinv*(x@W_pre^T + b_pre) ----------------

__global__ __launch_bounds__(256) void gemm_mfma_kernel(
    const float* __restrict__ Xf, const short* __restrict__ Wt,
    const float* __restrict__ bias, const float* __restrict__ dinv,
    short* __restrict__ Y, int M) {
  __shared__ short lds[4 * 32 * HID];  // 32 KB
  int t = threadIdx.x;
  int wave = t >> 6, l = t & 63;
  int lg = l >> 4, lr = l & 15;
  int mb = blockIdx.x * 128 + wave * 32;

  const f32x4 z4 = {0.f, 0.f, 0.f, 0.f};
  f32x4 acc[2][8];
  #pragma unroll
  for (int i = 0; i < 2; ++i)
    #pragma unroll
    for (int j = 0; j < 8; ++j) acc[i][j] = z4;

  #pragma unroll
  for (int kk = 0; kk < 4; ++kk) {
    int k0 = kk * 32 + lg * 8;
    s16x8 a[2];
    #pragma unroll
    for (int mf = 0; mf < 2; ++mf) {
      int row = mb + mf * 16 + lr;
      s16x8 av = {0, 0, 0, 0, 0, 0, 0, 0};
      if (row < M) {
        const float4* p = (const float4*)(Xf + (size_t)row * HID + k0);
        float4 x0 = p[0], x1 = p[1];
        av[0] = f2b(x0.x); av[1] = f2b(x0.y); av[2] = f2b(x0.z); av[3] = f2b(x0.w);
        av[4] = f2b(x1.x); av[5] = f2b(x1.y); av[6] = f2b(x1.z); av[7] = f2b(x1.w);
      }
      a[mf] = av;
    }
    #pragma unroll
    for (int nf = 0; nf < 8; ++nf) {
      s16x8 b = *(const s16x8*)(Wt + (size_t)(nf * 16 + lr) * HID + k0);
      acc[0][nf] = __builtin_amdgcn_mfma_f32_16x16x32_bf16(a[0], b, acc[0][nf], 0, 0, 0);
      acc[1][nf] = __builtin_amdgcn_mfma_f32_16x16x32_bf16(a[1], b, acc[1][nf], 0, 0, 0);
    }
  }

  float bv[8];
  #pragma unroll
  for (int nf = 0; nf < 8; ++nf) bv[nf] = bias[nf * 16 + lr];

  short* wsl = lds + wave * 32 * HID;
  #pragma unroll
  for (int mf = 0; mf < 2; ++mf) {
    #pragma unroll
    for (int r = 0; r < 4; ++r) {
      int ri = mf * 16 + lg * 4 + r;
      int row = mb + ri;
      float dv = (row < M) ? dinv[row] : 1.f;
      #pragma unroll
      for (int nf = 0; nf < 8; ++nf) {
        float v = (acc[mf][nf][r] + bv[nf]) * dv;
        wsl[ri * HID + nf * 16 + lr] = f2b(v);
      }
    }
  }
  __syncthreads();

  #pragma unroll
  for (int it = 0; it < 8; ++it) {
    int ro = it * 4 + lg;
    int row = mb + ro;
    s16x8 v = *(const s16x8*)(wsl + it * 512 + l * 8);
    if (row < M) *(s16x8*)(Y + (size_t)row * HID + lr * 8) = v;
  }
}

// ---------------- FUSED cell: gather(S_in) -> GEMM(W) -> +b -> LN -> ReLU -> S_out ----------------
// Static: 16 nodes/block, 256 threads / 4 waves; one node per 16-lane sub-group,
// gather unrolled x8. Self-row kept in registers (phase-3 mode-1 reuses it: the
// phase-1 owner thread of (node rowL, chunk lr) IS the phase-3 writer of (row, qq=lr)).
// Phase 2: 16x128 GEMM; wave w owns cols w*32..w*32+31 (2 col-frags, 8 MFMAs).
// mode 0: S_out = dinv*y;  mode 1: S_out = S_in + dinv*y;  mode 2: S_out = y (final).

__global__ __launch_bounds__(256) void cell_kernel(
    const short* __restrict__ Sin, const int* __restrict__ start,
    const int* __restrict__ deg, const float* __restrict__ dinv,
    const int* __restrict__ col, const int* __restrict__ perm,
    const short* __restrict__ Wt, const float* __restrict__ bconv,
    const float* __restrict__ lng, const float* __restrict__ lnb,
    short* __restrict__ Sout, int N, int mode) {
  __shared__ short Zs[16 * HID];       // 4 KB
  __shared__ float red[16][4][2];      // 512 B
  int t = threadIdx.x;
  int wave = t >> 6, l = t & 63, lr = l & 15, sub = l >> 4;
  const uint4* GR = (const uint4*)Sin;

  // ---- phase 1: each 16-lane sub-group gathers one node, 8 loads in flight ----
  int rowL = wave * 4 + sub;
  int slot = blockIdx.x * 16 + rowL;
  int v = (slot < N) ? perm[slot] : -1;
  int zofs = rowL * HID + ((lr * 8) ^ ((rowL & 7) << 3));  // swizzled short index
  uint4 selfrow = make_uint4(0u, 0u, 0u, 0u);
  float dv_self = 0.f;
  if (v >= 0) {
    selfrow = GR[(size_t)v * 16 + lr];  // self loop (kept for phase 3)
    f32x2 a0 = up2(selfrow.x), a1 = up2(selfrow.y), a2 = up2(selfrow.z), a3 = up2(selfrow.w);
    int lo = start[v], hi = lo + deg[v];
    int j = lo;
    for (; j + 8 <= hi; j += 8) {
      int c0 = col[j],     c1 = col[j + 1], c2 = col[j + 2], c3 = col[j + 3];
      int c4 = col[j + 4], c5 = col[j + 5], c6 = col[j + 6], c7 = col[j + 7];
      uint4 u0 = GR[(size_t)c0 * 16 + lr];
      uint4 u1 = GR[(size_t)c1 * 16 + lr];
      uint4 u2 = GR[(size_t)c2 * 16 + lr];
      uint4 u3 = GR[(size_t)c3 * 16 + lr];
      uint4 u4 = GR[(size_t)c4 * 16 + lr];
      uint4 u5 = GR[(size_t)c5 * 16 + lr];
      uint4 u6 = GR[(size_t)c6 * 16 + lr];
      uint4 u7 = GR[(size_t)c7 * 16 + lr];
      a0 += up2(u0.x) + up2(u1.x);  a1 += up2(u0.y) + up2(u1.y);
      a2 += up2(u0.z) + up2(u1.z);  a3 += up2(u0.w) + up2(u1.w);
      a0 += up2(u2.x) + up2(u3.x);  a1 += up2(u2.y) + up2(u3.y);
      a2 += up2(u2.z) + up2(u3.z);  a3 += up2(u2.w) + up2(u3.w);
      a0 += up2(u4.x) + up2(u5.x);  a1 += up2(u4.y) + up2(u5.y);
      a2 += up2(u4.z) + up2(u5.z);  a3 += up2(u4.w) + up2(u5.w);
      a0 += up2(u6.x) + up2(u7.x);  a1 += up2(u6.y) + up2(u7.y);
      a2 += up2(u6.z) + up2(u7.z);  a3 += up2(u6.w) + up2(u7.w);
    }
    if (j + 4 <= hi) {
      int c0 = col[j], c1 = col[j + 1], c2 = col[j + 2], c3 = col[j + 3];
      uint4 u0 = GR[(size_t)c0 * 16 + lr];
      uint4 u1 = GR[(size_t)c1 * 16 + lr];
      uint4 u2 = GR[(size_t)c2 * 16 + lr];
      uint4 u3 = GR[(size_t)c3 * 16 + lr];
      a0 += up2(u0.x) + up2(u1.x);  a1 += up2(u0.y) + up2(u1.y);
      a2 += up2(u0.z) + up2(u1.z);  a3 += up2(u0.w) + up2(u1.w);
      a0 += up2(u2.x) + up2(u3.x);  a1 += up2(u2.y) + up2(u3.y);
      a2 += up2(u2.z) + up2(u3.z);  a3 += up2(u2.w) + up2(u3.w);
      j += 4;
    }
    for (; j < hi; ++j) {
      uint4 u0 = GR[(size_t)col[j] * 16 + lr];
      a0 += up2(u0.x); a1 += up2(u0.y); a2 += up2(u0.z); a3 += up2(u0.w);
    }
    float d = dinv[v];
    dv_self = d;
    uint4 q;
    q.x = pack2(a0.x * d, a0.y * d);
    q.y = pack2(a1.x * d, a1.y * d);
    q.z = pack2(a2.x * d, a2.y * d);
    q.w = pack2(a3.x * d, a3.y * d);
    *(uint4*)&Zs[zofs] = q;
  } else {
    *(uint4*)&Zs[zofs] = make_uint4(0u, 0u, 0u, 0u);
  }
  __syncthreads();

  // ---- phase 2: 16x128 GEMM; wave w owns cols w*32..w*32+31 ----
  f32x4 acc0 = {0.f, 0.f, 0.f, 0.f}, acc1 = {0.f, 0.f, 0.f, 0.f};
  int base = wave * 32;
  #pragma unroll
  for (int kk = 0; kk < 4; ++kk) {
    int k0 = kk * 32 + sub * 8;
    s16x8 af = *(const s16x8*)&Zs[lr * HID + (k0 ^ ((lr & 7) << 3))];
    s16x8 bf0 = *(const s16x8*)(Wt + (size_t)(base + lr) * HID + k0);
    s16x8 bf1 = *(const s16x8*)(Wt + (size_t)(base + 16 + lr) * HID + k0);
    acc0 = __builtin_amdgcn_mfma_f32_16x16x32_bf16(af, bf0, acc0, 0, 0, 0);
    acc1 = __builtin_amdgcn_mfma_f32_16x16x32_bf16(af, bf1, acc1, 0, 0, 0);
  }
  int c0 = base + lr, c1 = base + 16 + lr;
  float bc0 = bconv[c0], bc1 = bconv[c1];
  float h0[4], h1[4], s1[4], s2[4];
  #pragma unroll
  for (int r = 0; r < 4; ++r) {
    h0[r] = acc0[r] + bc0;
    h1[r] = acc1[r] + bc1;
    s1[r] = h0[r] + h1[r];
    s2[r] = h0[r] * h0[r] + h1[r] * h1[r];
  }
  #pragma unroll
  for (int off = 1; off <= 8; off <<= 1) {
    #pragma unroll
    for (int r = 0; r < 4; ++r) {
      s1[r] += __shfl_xor(s1[r], off, 64);
      s2[r] += __shfl_xor(s2[r], off, 64);
    }
  }
  if (lr == 0) {
    #pragma unroll
    for (int r = 0; r < 4; ++r) {
      red[sub * 4 + r][wave][0] = s1[r];
      red[sub * 4 + r][wave][1] = s2[r];
    }
  }
  __syncthreads();
  float gl0 = lng[c0], bl0 = lnb[c0], gl1 = lng[c1], bl1 = lnb[c1];
  #pragma unroll
  for (int r = 0; r < 4; ++r) {
    int row = sub * 4 + r;
    const float4* rp = (const float4*)&red[row][0][0];
    float4 v0 = rp[0], v1 = rp[1];
    float t1 = v0.x + v0.z + v1.x + v1.z;
    float t2 = v0.y + v0.w + v1.y + v1.w;
    float mu = t1 * (1.f / HID);
    float var = t2 * (1.f / HID) - mu * mu;
    float inv = rsqrtf(fmaxf(var, 0.f) + LN_EPS);
    float yv0 = fmaxf(fmaf((h0[r] - mu) * inv, gl0, bl0), 0.f);
    float yv1 = fmaxf(fmaf((h1[r] - mu) * inv, gl1, bl1), 0.f);
    int sw = (row & 7) << 3;
    Zs[row * HID + (c0 ^ sw)] = f2b(yv0);
    Zs[row * HID + (c1 ^ sw)] = f2b(yv1);
  }
  __syncthreads();

  // ---- phase 3: write S_out. Thread (row=rowL, qq=lr) holds selfrow in regs. ----
  {
    int row = rowL, qq = lr;  // identical mapping to phase 1 ownership
    int slot2 = blockIdx.x * 16 + row;
    if (slot2 < N) {
      int v2 = v;  // same node
      s16x8 y8 = *(const s16x8*)&Zs[row * HID + ((qq * 8) ^ ((row & 7) << 3))];
      float yv[8];
      #pragma unroll
      for (int i = 0; i < 8; ++i) yv[i] = sb2f(y8[i]);
      uint4 o;
      if (mode == 2) {
        o.x = pack2(yv[0], yv[1]); o.y = pack2(yv[2], yv[3]);
        o.z = pack2(yv[4], yv[5]); o.w = pack2(yv[6], yv[7]);
      } else if (mode == 0) {
        float d = dv_self;
        o.x = pack2(yv[0] * d, yv[1] * d); o.y = pack2(yv[2] * d, yv[3] * d);
        o.z = pack2(yv[4] * d, yv[5] * d); o.w = pack2(yv[6] * d, yv[7] * d);
      } else {
        float d = dv_self;
        uint4 ui = selfrow;  // register reuse — no global re-read
        o.x = pack2(bl2f(ui.x) + yv[0] * d, bh2f(ui.x) + yv[1] * d);
        o.y = pack2(bl2f(ui.y) + yv[2] * d, bh2f(ui.y) + yv[3] * d);
        o.z = pack2(bl2f(ui.z) + yv[4] * d, bh2f(ui.z) + yv[5] * d);
        o.w = pack2(bl2f(ui.w) + yv[6] * d, bh2f(ui.w) + yv[7] * d);
      }
      ((uint4*)Sout)[(size_t)v2 * 16 + qq] = o;
    }
  }
}

// ---------------- pooling + post MLP ----------------

__device__ inline int lower_bound_i(const int* a, int n, int key) {
  int lo = 0, hi = n;
  while (lo < hi) { int m = (lo + hi) >> 1; if (a[m] < key) lo = m + 1; else hi = m; }
  return lo;
}

__global__ __launch_bounds__(128) void pool_post_kernel(
    const short* __restrict__ Yl, const int* __restrict__ batch, int n,
    const float* __restrict__ Wp, const float* __restrict__ bp,
    float* __restrict__ out, int n_out) {
  int g = blockIdx.x, t = threadIdx.x;
  int wave = t >> 6;
  int lr = t & 15, slot = t >> 4;
  int lo = lower_bound_i(batch, n, g);
  int hi = lower_bound_i(batch, n, g + 1);
  const uint4* YR = (const uint4*)Yl;
  float a[8] = {0.f, 0.f, 0.f, 0.f, 0.f, 0.f, 0.f, 0.f};
  for (int r = lo + slot; r < hi; r += 8) {
    uint4 u = YR[(size_t)r * 16 + lr];
    a[0] += bl2f(u.x); a[1] += bh2f(u.x);
    a[2] += bl2f(u.y); a[3] += bh2f(u.y);
    a[4] += bl2f(u.z); a[5] += bh2f(u.z);
    a[6] += bl2f(u.w); a[7] += bh2f(u.w);
  }
  #pragma unroll
  for (int i = 0; i < 8; ++i) {
    a[i] += __shfl_xor(a[i], 16, 64);
    a[i] += __shfl_xor(a[i], 32, 64);
  }
  __shared__ float ls[2][HID];
  if ((slot & 3) == 0) {
    #pragma unroll
    for (int i = 0; i < 8; ++i) ls[wave][8 * lr + i] = a[i];
  }
  __syncthreads();
  if (t < n_out) {
    float o = bp[t];
    #pragma unroll 8
    for (int k = 0; k < HID; ++k) o = fmaf(ls[0][k] + ls[1][k], Wp[k * n_out + t], o);
    out[g * n_out + t] = o;
  }
}

// ---------------- launch ----------------

extern "C" void kernel_launch(void* const* d_in, const int* in_sizes, int n_in,
                              void* d_out, int out_size, void* d_ws, size_t ws_size,
                              hipStream_t stream) {
  const float* x      = (const float*)d_in[0];
  const int*   ei     = (const int*)d_in[1];
  const int*   batch  = (const int*)d_in[2];
  const float* W_pre  = (const float*)d_in[3];
  const float* b_pre  = (const float*)d_in[4];
  const float* conv_W = (const float*)d_in[5];
  const float* conv_b = (const float*)d_in[6];
  const float* ln_g   = (const float*)d_in[7];
  const float* ln_b   = (const float*)d_in[8];
  const float* W_post = (const float*)d_in[9];
  const float* b_post = (const float*)d_in[10];
  float* out = (float*)d_out;

  const int N = in_sizes[2];          // 50000
  const int E = in_sizes[1] / 2;      // 600000
  const int OUT_DIM = 10;
  const int NG = out_size / OUT_DIM;  // 512

  // workspace carve (all 16B-aligned)
  char* p = (char*)d_ws;
  short* SA  = (short*)p;            p += (size_t)N * HID * 2;   // bf16
  short* SB  = (short*)p;            p += (size_t)N * HID * 2;   // bf16
  short* Wt  = (short*)p;            p += (size_t)5 * HID * HID * 2;
  float* dinv = (float*)p;           p += (size_t)N * 4;
  // contiguous zero region: deg[N], cnt[1], pad[7], hist[64*16]
  int* deg   = (int*)p;              p += (size_t)(N + 8 + 64 * 16) * 4;
  int* cnt   = deg + N;
  int* hist  = deg + N + 8;
  int* startv = (int*)p;             p += (size_t)N * 4;
  int* cur   = (int*)p;              p += (size_t)N * 4;
  int* col   = (int*)p;              p += (size_t)E * 4;
  int* perm  = (int*)p;              p += (size_t)N * 4;
  int* bincur = (int*)p;             p += 64 * 16 * 4;

  const int* srcp = ei;
  const int* dstp = ei + E;

  int zero_n = N + 8 + 64 * 16;
  int nb256 = (N + 255) / 256;
  int eb256 = (E + 255) / 256;
  int gemm_grid = (N + 127) / 128;
  int cell_grid = (N + 15) / 16;
  int scat_grid = (N + SNODES - 1) / SNODES;

  // weight prep (W_pre + 4 conv weights)
  prep_w_kernel<<<5 * HID, 64, 0, stream>>>(W_pre, conv_W, Wt);

  // CSR + dinv (scan-free) + cheap degree sort
  zero_ints_kernel<<<(zero_n + 255) / 256, 256, 0, stream>>>(deg, zero_n);
  deg_count_kernel<<<eb256, 256, 0, stream>>>(dstp, E, deg);
  alloc_kernel<<<nb256, 256, 0, stream>>>(deg, startv, cur, dinv, cnt, hist, N);
  fill_csr_kernel<<<eb256, 256, 0, stream>>>(srcp, dstp, E, cur, col);
  binoff_kernel<<<1, 64, 0, stream>>>(hist, bincur);
  scatter_kernel<<<scat_grid, 256, 0, stream>>>(deg, bincur, perm, N);

  // S0 = dinv * (x @ W_pre + b_pre)  -> SA
  gemm_mfma_kernel<<<gemm_grid, 256, 0, stream>>>(x, Wt + 0 * 16384, b_pre, dinv, SA, N);

  // cell 0: SA -> SB = dinv*y0
  cell_kernel<<<cell_grid, 256, 0, stream>>>(SA, startv, deg, dinv, col, perm, Wt + 1 * 16384,
                                             conv_b + 0 * HID, ln_g + 0 * HID, ln_b + 0 * HID,
                                             SB, N, 0);
  // cell 1: SB -> SA = SB + dinv*y1
  cell_kernel<<<cell_grid, 256, 0, stream>>>(SB, startv, deg, dinv, col, perm, Wt + 2 * 16384,
                                             conv_b + 1 * HID, ln_g + 1 * HID, ln_b + 1 * HID,
                                             SA, N, 1);
  // cell 2: SA -> SB = SA + dinv*y2
  cell_kernel<<<cell_grid, 256, 0, stream>>>(SA, startv, deg, dinv, col, perm, Wt + 3 * 16384,
                                             conv_b + 2 * HID, ln_g + 2 * HID, ln_b + 2 * HID,
                                             SB, N, 1);
  // cell 3: SB -> SA = y3 (unscaled, pooling source)
  cell_kernel<<<cell_grid, 256, 0, stream>>>(SB, startv, deg, dinv, col, perm, Wt + 4 * 16384,
                                             conv_b + 3 * HID, ln_g + 3 * HID, ln_b + 3 * HID,
                                             SA, N, 2);

  // pooling + post MLP
  pool_post_kernel<<<NG, 128, 0, stream>>>(SA, batch, N, W_post, b_post, out, OUT_DIM);
}

// Round 13
// 254.395 us; speedup vs baseline: 1.0538x; 1.0538x over previous
//
#include <hip/hip_runtime.h>

#define HID 128
#define LN_EPS 1e-5f

using f32x2 = __attribute__((ext_vector_type(2))) float;
using f32x4 = __attribute__((ext_vector_type(4))) float;
using s16x8 = __attribute__((ext_vector_type(8))) short;

__device__ inline float bl2f(unsigned u) { u <<= 16; return __builtin_bit_cast(float, u); }
__device__ inline float bh2f(unsigned u) { u &= 0xffff0000u; return __builtin_bit_cast(float, u); }
__device__ inline float sb2f(short s) {
  unsigned u = ((unsigned)(unsigned short)s) << 16;
  return __builtin_bit_cast(float, u);
}
__device__ inline unsigned f2b_bits(float f) {
  unsigned u = __builtin_bit_cast(unsigned, f);
  return (u + 0x7fffu + ((u >> 16) & 1u)) >> 16;  // RNE
}
__device__ inline short f2b(float f) { return (short)f2b_bits(f); }
__device__ inline unsigned pack2(float a, float b) { return f2b_bits(a) | (f2b_bits(b) << 16); }
__device__ inline f32x2 up2(unsigned u) {
  f32x2 r; r.x = bl2f(u); r.y = bh2f(u); return r;
}

// ---------------- weight prep: Wt[w][n][k] = bf16(src_w[k][n]); w=0 -> W_pre, w>=1 -> conv_W[w-1] ----------------

__global__ __launch_bounds__(64) void prep_w_kernel(const float* __restrict__ W_pre,
                                                    const float* __restrict__ conv_W,
                                                    short* __restrict__ Wt) {
  int b = blockIdx.x;            // 0..639
  int w = b >> 7, n = b & 127;
  const float* W = (w == 0) ? W_pre : conv_W + (size_t)(w - 1) * HID * HID;
  int t = threadIdx.x;           // k = 2t, 2t+1
  float f0 = W[(2 * t) * HID + n];
  float f1 = W[(2 * t + 1) * HID + n];
  ((unsigned*)Wt)[(size_t)(w * HID + n) * 64 + t] = pack2(f0, f1);
}

// ---------------- CSR build (scan-free) + degree-sort ----------------

__global__ void zero_ints_kernel(int* __restrict__ p, int n) {
  int i = blockIdx.x * blockDim.x + threadIdx.x;
  if (i < n) p[i] = 0;
}

__global__ void deg_count_kernel(const int* __restrict__ dst, int E, int* __restrict__ deg) {
  int e = blockIdx.x * blockDim.x + threadIdx.x;
  if (e < E) atomicAdd(&deg[dst[e]], 1);
}

// block scan for CSR offsets + dinv + LDS-private degree histogram (64B-padded global bins)
__global__ __launch_bounds__(256) void alloc_kernel(const int* __restrict__ deg,
                                                    int* __restrict__ start,
                                                    int* __restrict__ cur,
                                                    float* __restrict__ dinv,
                                                    int* __restrict__ cnt,
                                                    int* __restrict__ hist, int n) {
  __shared__ int wt[4];
  __shared__ int bbase;
  __shared__ int lh[64];
  int t = threadIdx.x, lane = t & 63, wid = t >> 6;
  if (t < 64) lh[t] = 0;
  int i = blockIdx.x * 256 + t;
  int d = (i < n) ? deg[i] : 0;
  int x = d;
  #pragma unroll
  for (int off = 1; off < 64; off <<= 1) {
    int u = __shfl_up(x, off, 64);
    if (lane >= off) x += u;
  }
  if (lane == 63) wt[wid] = x;
  __syncthreads();
  if (i < n) atomicAdd(&lh[min(d, 63)], 1);
  if (t == 0) bbase = atomicAdd(cnt, wt[0] + wt[1] + wt[2] + wt[3]);
  __syncthreads();
  int wbase = bbase;
  for (int w = 0; w < wid; ++w) wbase += wt[w];
  int excl = wbase + x - d;
  if (i < n) {
    start[i] = excl;
    cur[i] = excl;
    dinv[i] = rsqrtf((float)(d + 1));
  }
  if (t < 64 && lh[t]) atomicAdd(&hist[t * 16], lh[t]);
}

__global__ void fill_csr_kernel(const int* __restrict__ src, const int* __restrict__ dst,
                                int E, int* __restrict__ cur, int* __restrict__ col) {
  int e = blockIdx.x * blockDim.x + threadIdx.x;
  if (e < E) {
    int d = dst[e];
    int p = atomicAdd(&cur[d], 1);
    col[p] = src[e];
  }
}

// descending-degree bin offsets (heavy bins first so straggler blocks start early)
__global__ __launch_bounds__(64) void binoff_kernel(const int* __restrict__ hist,
                                                    int* __restrict__ bincur) {
  int lane = threadIdx.x;    // 0..63
  int rb = 63 - lane;        // bin 63 gets offset 0
  int v = hist[rb * 16];
  int x = v;
  #pragma unroll
  for (int off = 1; off < 64; off <<= 1) {
    int u = __shfl_up(x, off, 64);
    if (lane >= off) x += u;
  }
  bincur[rb * 16] = x - v;
}

// Per-block LDS ranking + one padded global atomic per bin per block.
#define SNODES 1024
__global__ __launch_bounds__(256) void scatter_kernel(const int* __restrict__ deg,
                                                      int* __restrict__ bincur,
                                                      int* __restrict__ perm, int n) {
  __shared__ int lh[64];
  __shared__ int lbase[64];
  int t = threadIdx.x;
  if (t < 64) lh[t] = 0;
  __syncthreads();
  int nstart = blockIdx.x * SNODES;
  int nend = min(n, nstart + SNODES);
  int myb[4], myrank[4];
  int cnt = 0;
  for (int i = nstart + t; i < nend; i += 256) {
    int b = min(deg[i], 63);
    myb[cnt] = b;
    myrank[cnt] = atomicAdd(&lh[b], 1);
    ++cnt;
  }
  __syncthreads();
  if (t < 64) lbase[t] = lh[t] ? atomicAdd(&bincur[t * 16], lh[t]) : 0;
  __syncthreads();
  int k = 0;
  for (int i = nstart + t; i < nend; i += 256, ++k)
    perm[lbase[myb[k]] + myrank[k]] = i;
}

// ---------------- MFMA GEMM (pre): S0 = dinv*(x@W_pre^T + b_pre) ----------------

__global__ __launch_bounds__(256) void gemm_mfma_kernel(
    const float* __restrict__ Xf, const short* __restrict__ Wt,
    const float* __restrict__ bias, const float* __restrict__ dinv,
    short* __restrict__ Y, int M) {
  __shared__ short lds[4 * 32 * HID];  // 32 KB
  int t = threadIdx.x;
  int wave = t >> 6, l = t & 63;
  int lg = l >> 4, lr = l & 15;
  int mb = blockIdx.x * 128 + wave * 32;

  const f32x4 z4 = {0.f, 0.f, 0.f, 0.f};
  f32x4 acc[2][8];
  #pragma unroll
  for (int i = 0; i < 2; ++i)
    #pragma unroll
    for (int j = 0; j < 8; ++j) acc[i][j] = z4;

  #pragma unroll
  for (int kk = 0; kk < 4; ++kk) {
    int k0 = kk * 32 + lg * 8;
    s16x8 a[2];
    #pragma unroll
    for (int mf = 0; mf < 2; ++mf) {
      int row = mb + mf * 16 + lr;
      s16x8 av = {0, 0, 0, 0, 0, 0, 0, 0};
      if (row < M) {
        const float4* p = (const float4*)(Xf + (size_t)row * HID + k0);
        float4 x0 = p[0], x1 = p[1];
        av[0] = f2b(x0.x); av[1] = f2b(x0.y); av[2] = f2b(x0.z); av[3] = f2b(x0.w);
        av[4] = f2b(x1.x); av[5] = f2b(x1.y); av[6] = f2b(x1.z); av[7] = f2b(x1.w);
      }
      a[mf] = av;
    }
    #pragma unroll
    for (int nf = 0; nf < 8; ++nf) {
      s16x8 b = *(const s16x8*)(Wt + (size_t)(nf * 16 + lr) * HID + k0);
      acc[0][nf] = __builtin_amdgcn_mfma_f32_16x16x32_bf16(a[0], b, acc[0][nf], 0, 0, 0);
      acc[1][nf] = __builtin_amdgcn_mfma_f32_16x16x32_bf16(a[1], b, acc[1][nf], 0, 0, 0);
    }
  }

  float bv[8];
  #pragma unroll
  for (int nf = 0; nf < 8; ++nf) bv[nf] = bias[nf * 16 + lr];

  short* wsl = lds + wave * 32 * HID;
  #pragma unroll
  for (int mf = 0; mf < 2; ++mf) {
    #pragma unroll
    for (int r = 0; r < 4; ++r) {
      int ri = mf * 16 + lg * 4 + r;
      int row = mb + ri;
      float dv = (row < M) ? dinv[row] : 1.f;
      #pragma unroll
      for (int nf = 0; nf < 8; ++nf) {
        float v = (acc[mf][nf][r] + bv[nf]) * dv;
        wsl[ri * HID + nf * 16 + lr] = f2b(v);
      }
    }
  }
  __syncthreads();

  #pragma unroll
  for (int it = 0; it < 8; ++it) {
    int ro = it * 4 + lg;
    int row = mb + ro;
    s16x8 v = *(const s16x8*)(wsl + it * 512 + l * 8);
    if (row < M) *(s16x8*)(Y + (size_t)row * HID + lr * 8) = v;
  }
}

// ---------------- FUSED cell: gather(S_in) -> GEMM(W) -> +b -> LN -> ReLU -> S_out ----------------
// Static: 16 nodes/block, 256 threads / 4 waves; one node per 16-lane sub-group,
// gather unrolled x8 (deg-sorted streams). Self-row kept in registers: the phase-1
// owner thread of (node rowL, chunk lr) IS the phase-3 writer of (row=rowL, qq=lr),
// so mode-1 avoids re-reading Sin[v] from global.
// Phase 2: 16x128 GEMM; wave w owns cols w*32..w*32+31 (2 col-frags, 8 MFMAs).
// mode 0: S_out = dinv*y;  mode 1: S_out = S_in + dinv*y;  mode 2: S_out = y (final).

__global__ __launch_bounds__(256, 6) void cell_kernel(
    const short* __restrict__ Sin, const int* __restrict__ start,
    const int* __restrict__ deg, const float* __restrict__ dinv,
    const int* __restrict__ col, const int* __restrict__ perm,
    const short* __restrict__ Wt, const float* __restrict__ bconv,
    const float* __restrict__ lng, const float* __restrict__ lnb,
    short* __restrict__ Sout, int N, int mode) {
  __shared__ short Zs[16 * HID];       // 4 KB
  __shared__ float red[16][4][2];      // 512 B
  int t = threadIdx.x;
  int wave = t >> 6, l = t & 63, lr = l & 15, sub = l >> 4;
  const uint4* GR = (const uint4*)Sin;

  // ---- phase 1: each 16-lane sub-group gathers one node, 8 loads in flight ----
  int rowL = wave * 4 + sub;
  int slot = blockIdx.x * 16 + rowL;
  int v = (slot < N) ? perm[slot] : -1;
  int zofs = rowL * HID + ((lr * 8) ^ ((rowL & 7) << 3));  // swizzled short index
  uint4 selfrow = make_uint4(0u, 0u, 0u, 0u);
  float dv_self = 0.f;
  if (v >= 0) {
    selfrow = GR[(size_t)v * 16 + lr];  // self loop (kept for phase 3)
    f32x2 a0 = up2(selfrow.x), a1 = up2(selfrow.y), a2 = up2(selfrow.z), a3 = up2(selfrow.w);
    int lo = start[v], hi = lo + deg[v];
    int j = lo;
    for (; j + 8 <= hi; j += 8) {
      int c0 = col[j],     c1 = col[j + 1], c2 = col[j + 2], c3 = col[j + 3];
      int c4 = col[j + 4], c5 = col[j + 5], c6 = col[j + 6], c7 = col[j + 7];
      uint4 u0 = GR[(size_t)c0 * 16 + lr];
      uint4 u1 = GR[(size_t)c1 * 16 + lr];
      uint4 u2 = GR[(size_t)c2 * 16 + lr];
      uint4 u3 = GR[(size_t)c3 * 16 + lr];
      uint4 u4 = GR[(size_t)c4 * 16 + lr];
      uint4 u5 = GR[(size_t)c5 * 16 + lr];
      uint4 u6 = GR[(size_t)c6 * 16 + lr];
      uint4 u7 = GR[(size_t)c7 * 16 + lr];
      a0 += up2(u0.x) + up2(u1.x);  a1 += up2(u0.y) + up2(u1.y);
      a2 += up2(u0.z) + up2(u1.z);  a3 += up2(u0.w) + up2(u1.w);
      a0 += up2(u2.x) + up2(u3.x);  a1 += up2(u2.y) + up2(u3.y);
      a2 += up2(u2.z) + up2(u3.z);  a3 += up2(u2.w) + up2(u3.w);
      a0 += up2(u4.x) + up2(u5.x);  a1 += up2(u4.y) + up2(u5.y);
      a2 += up2(u4.z) + up2(u5.z);  a3 += up2(u4.w) + up2(u5.w);
      a0 += up2(u6.x) + up2(u7.x);  a1 += up2(u6.y) + up2(u7.y);
      a2 += up2(u6.z) + up2(u7.z);  a3 += up2(u6.w) + up2(u7.w);
    }
    if (j + 4 <= hi) {
      int c0 = col[j], c1 = col[j + 1], c2 = col[j + 2], c3 = col[j + 3];
      uint4 u0 = GR[(size_t)c0 * 16 + lr];
      uint4 u1 = GR[(size_t)c1 * 16 + lr];
      uint4 u2 = GR[(size_t)c2 * 16 + lr];
      uint4 u3 = GR[(size_t)c3 * 16 + lr];
      a0 += up2(u0.x) + up2(u1.x);  a1 += up2(u0.y) + up2(u1.y);
      a2 += up2(u0.z) + up2(u1.z);  a3 += up2(u0.w) + up2(u1.w);
      a0 += up2(u2.x) + up2(u3.x);  a1 += up2(u2.y) + up2(u3.y);
      a2 += up2(u2.z) + up2(u3.z);  a3 += up2(u2.w) + up2(u3.w);
      j += 4;
    }
    for (; j < hi; ++j) {
      uint4 u0 = GR[(size_t)col[j] * 16 + lr];
      a0 += up2(u0.x); a1 += up2(u0.y); a2 += up2(u0.z); a3 += up2(u0.w);
    }
    float d = dinv[v];
    dv_self = d;
    uint4 q;
    q.x = pack2(a0.x * d, a0.y * d);
    q.y = pack2(a1.x * d, a1.y * d);
    q.z = pack2(a2.x * d, a2.y * d);
    q.w = pack2(a3.x * d, a3.y * d);
    *(uint4*)&Zs[zofs] = q;
  } else {
    *(uint4*)&Zs[zofs] = make_uint4(0u, 0u, 0u, 0u);
  }
  __syncthreads();

  // ---- phase 2: 16x128 GEMM; wave w owns cols w*32..w*32+31 ----
  f32x4 acc0 = {0.f, 0.f, 0.f, 0.f}, acc1 = {0.f, 0.f, 0.f, 0.f};
  int base = wave * 32;
  #pragma unroll
  for (int kk = 0; kk < 4; ++kk) {
    int k0 = kk * 32 + sub * 8;
    s16x8 af = *(const s16x8*)&Zs[lr * HID + (k0 ^ ((lr & 7) << 3))];
    s16x8 bf0 = *(const s16x8*)(Wt + (size_t)(base + lr) * HID + k0);
    s16x8 bf1 = *(const s16x8*)(Wt + (size_t)(base + 16 + lr) * HID + k0);
    acc0 = __builtin_amdgcn_mfma_f32_16x16x32_bf16(af, bf0, acc0, 0, 0, 0);
    acc1 = __builtin_amdgcn_mfma_f32_16x16x32_bf16(af, bf1, acc1, 0, 0, 0);
  }
  int c0 = base + lr, c1 = base + 16 + lr;
  float bc0 = bconv[c0], bc1 = bconv[c1];
  float h0[4], h1[4], s1[4], s2[4];
  #pragma unroll
  for (int r = 0; r < 4; ++r) {
    h0[r] = acc0[r] + bc0;
    h1[r] = acc1[r] + bc1;
    s1[r] = h0[r] + h1[r];
    s2[r] = h0[r] * h0[r] + h1[r] * h1[r];
  }
  #pragma unroll
  for (int off = 1; off <= 8; off <<= 1) {
    #pragma unroll
    for (int r = 0; r < 4; ++r) {
      s1[r] += __shfl_xor(s1[r], off, 64);
      s2[r] += __shfl_xor(s2[r], off, 64);
    }
  }
  if (lr == 0) {
    #pragma unroll
    for (int r = 0; r < 4; ++r) {
      red[sub * 4 + r][wave][0] = s1[r];
      red[sub * 4 + r][wave][1] = s2[r];
    }
  }
  __syncthreads();
  float gl0 = lng[c0], bl0 = lnb[c0], gl1 = lng[c1], bl1 = lnb[c1];
  #pragma unroll
  for (int r = 0; r < 4; ++r) {
    int row = sub * 4 + r;
    const float4* rp = (const float4*)&red[row][0][0];
    float4 v0 = rp[0], v1 = rp[1];
    float t1 = v0.x + v0.z + v1.x + v1.z;
    float t2 = v0.y + v0.w + v1.y + v1.w;
    float mu = t1 * (1.f / HID);
    float var = t2 * (1.f / HID) - mu * mu;
    float inv = rsqrtf(fmaxf(var, 0.f) + LN_EPS);
    float yv0 = fmaxf(fmaf((h0[r] - mu) * inv, gl0, bl0), 0.f);
    float yv1 = fmaxf(fmaf((h1[r] - mu) * inv, gl1, bl1), 0.f);
    int sw = (row & 7) << 3;
    Zs[row * HID + (c0 ^ sw)] = f2b(yv0);
    Zs[row * HID + (c1 ^ sw)] = f2b(yv1);
  }
  __syncthreads();

  // ---- phase 3: write S_out. Thread (row=rowL, qq=lr) holds selfrow in regs. ----
  {
    int row = rowL, qq = lr;  // identical mapping to phase 1 ownership
    if (v >= 0) {
      s16x8 y8 = *(const s16x8*)&Zs[row * HID + ((qq * 8) ^ ((row & 7) << 3))];
      float yv[8];
      #pragma unroll
      for (int i = 0; i < 8; ++i) yv[i] = sb2f(y8[i]);
      uint4 o;
      if (mode == 2) {
        o.x = pack2(yv[0], yv[1]); o.y = pack2(yv[2], yv[3]);
        o.z = pack2(yv[4], yv[5]); o.w = pack2(yv[6], yv[7]);
      } else if (mode == 0) {
        float d = dv_self;
        o.x = pack2(yv[0] * d, yv[1] * d); o.y = pack2(yv[2] * d, yv[3] * d);
        o.z = pack2(yv[4] * d, yv[5] * d); o.w = pack2(yv[6] * d, yv[7] * d);
      } else {
        float d = dv_self;
        uint4 ui = selfrow;  // register reuse — no global re-read
        o.x = pack2(bl2f(ui.x) + yv[0] * d, bh2f(ui.x) + yv[1] * d);
        o.y = pack2(bl2f(ui.y) + yv[2] * d, bh2f(ui.y) + yv[3] * d);
        o.z = pack2(bl2f(ui.z) + yv[4] * d, bh2f(ui.z) + yv[5] * d);
        o.w = pack2(bl2f(ui.w) + yv[6] * d, bh2f(ui.w) + yv[7] * d);
      }
      ((uint4*)Sout)[(size_t)v * 16 + qq] = o;
    }
  }
}

// ---------------- pooling + post MLP ----------------

__device__ inline int lower_bound_i(const int* a, int n, int key) {
  int lo = 0, hi = n;
  while (lo < hi) { int m = (lo + hi) >> 1; if (a[m] < key) lo = m + 1; else hi = m; }
  return lo;
}

__global__ __launch_bounds__(128) void pool_post_kernel(
    const short* __restrict__ Yl, const int* __restrict__ batch, int n,
    const float* __restrict__ Wp, const float* __restrict__ bp,
    float* __restrict__ out, int n_out) {
  int g = blockIdx.x, t = threadIdx.x;
  int wave = t >> 6;
  int lr = t & 15, slot = t >> 4;
  int lo = lower_bound_i(batch, n, g);
  int hi = lower_bound_i(batch, n, g + 1);
  const uint4* YR = (const uint4*)Yl;
  float a[8] = {0.f, 0.f, 0.f, 0.f, 0.f, 0.f, 0.f, 0.f};
  for (int r = lo + slot; r < hi; r += 8) {
    uint4 u = YR[(size_t)r * 16 + lr];
    a[0] += bl2f(u.x); a[1] += bh2f(u.x);
    a[2] += bl2f(u.y); a[3] += bh2f(u.y);
    a[4] += bl2f(u.z); a[5] += bh2f(u.z);
    a[6] += bl2f(u.w); a[7] += bh2f(u.w);
  }
  #pragma unroll
  for (int i = 0; i < 8; ++i) {
    a[i] += __shfl_xor(a[i], 16, 64);
    a[i] += __shfl_xor(a[i], 32, 64);
  }
  __shared__ float ls[2][HID];
  if ((slot & 3) == 0) {
    #pragma unroll
    for (int i = 0; i < 8; ++i) ls[wave][8 * lr + i] = a[i];
  }
  __syncthreads();
  if (t < n_out) {
    float o = bp[t];
    #pragma unroll 8
    for (int k = 0; k < HID; ++k) o = fmaf(ls[0][k] + ls[1][k], Wp[k * n_out + t], o);
    out[g * n_out + t] = o;
  }
}

// ---------------- launch ----------------

extern "C" void kernel_launch(void* const* d_in, const int* in_sizes, int n_in,
                              void* d_out, int out_size, void* d_ws, size_t ws_size,
                              hipStream_t stream) {
  const float* x      = (const float*)d_in[0];
  const int*   ei     = (const int*)d_in[1];
  const int*   batch  = (const int*)d_in[2];
  const float* W_pre  = (const float*)d_in[3];
  const float* b_pre  = (const float*)d_in[4];
  const float* conv_W = (const float*)d_in[5];
  const float* conv_b = (const float*)d_in[6];
  const float* ln_g   = (const float*)d_in[7];
  const float* ln_b   = (const float*)d_in[8];
  const float* W_post = (const float*)d_in[9];
  const float* b_post = (const float*)d_in[10];
  float* out = (float*)d_out;

  const int N = in_sizes[2];          // 50000
  const int E = in_sizes[1] / 2;      // 600000
  const int OUT_DIM = 10;
  const int NG = out_size / OUT_DIM;  // 512

  // workspace carve (all 16B-aligned)
  char* p = (char*)d_ws;
  short* SA  = (short*)p;            p += (size_t)N * HID * 2;   // bf16
  short* SB  = (short*)p;            p += (size_t)N * HID * 2;   // bf16
  short* Wt  = (short*)p;            p += (size_t)5 * HID * HID * 2;
  float* dinv = (float*)p;           p += (size_t)N * 4;
  // contiguous zero region: deg[N], cnt[1], pad[7], hist[64*16]
  int* deg   = (int*)p;              p += (size_t)(N + 8 + 64 * 16) * 4;
  int* cnt   = deg + N;
  int* hist  = deg + N + 8;
  int* startv = (int*)p;             p += (size_t)N * 4;
  int* cur   = (int*)p;              p += (size_t)N * 4;
  int* col   = (int*)p;              p += (size_t)E * 4;
  int* perm  = (int*)p;              p += (size_t)N * 4;
  int* bincur = (int*)p;             p += 64 * 16 * 4;

  const int* srcp = ei;
  const int* dstp = ei + E;

  int zero_n = N + 8 + 64 * 16;
  int nb256 = (N + 255) / 256;
  int eb256 = (E + 255) / 256;
  int gemm_grid = (N + 127) / 128;
  int cell_grid = (N + 15) / 16;
  int scat_grid = (N + SNODES - 1) / SNODES;

  // weight prep (W_pre + 4 conv weights)
  prep_w_kernel<<<5 * HID, 64, 0, stream>>>(W_pre, conv_W, Wt);

  // CSR + dinv (scan-free) + cheap degree sort
  zero_ints_kernel<<<(zero_n + 255) / 256, 256, 0, stream>>>(deg, zero_n);
  deg_count_kernel<<<eb256, 256, 0, stream>>>(dstp, E, deg);
  alloc_kernel<<<nb256, 256, 0, stream>>>(deg, startv, cur, dinv, cnt, hist, N);
  fill_csr_kernel<<<eb256, 256, 0, stream>>>(srcp, dstp, E, cur, col);
  binoff_kernel<<<1, 64, 0, stream>>>(hist, bincur);
  scatter_kernel<<<scat_grid, 256, 0, stream>>>(deg, bincur, perm, N);

  // S0 = dinv * (x @ W_pre + b_pre)  -> SA
  gemm_mfma_kernel<<<gemm_grid, 256, 0, stream>>>(x, Wt + 0 * 16384, b_pre, dinv, SA, N);

  // cell 0: SA -> SB = dinv*y0
  cell_kernel<<<cell_grid, 256, 0, stream>>>(SA, startv, deg, dinv, col, perm, Wt + 1 * 16384,
                                             conv_b + 0 * HID, ln_g + 0 * HID, ln_b + 0 * HID,
                                             SB, N, 0);
  // cell 1: SB -> SA = SB + dinv*y1
  cell_kernel<<<cell_grid, 256, 0, stream>>>(SB, startv, deg, dinv, col, perm, Wt + 2 * 16384,
                                             conv_b + 1 * HID, ln_g + 1 * HID, ln_b + 1 * HID,
                                             SA, N, 1);
  // cell 2: SA -> SB = SA + dinv*y2
  cell_kernel<<<cell_grid, 256, 0, stream>>>(SA, startv, deg, dinv, col, perm, Wt + 3 * 16384,
                                             conv_b + 2 * HID, ln_g + 2 * HID, ln_b + 2 * HID,
                                             SB, N, 1);
  // cell 3: SB -> SA = y3 (unscaled, pooling source)
  cell_kernel<<<cell_grid, 256, 0, stream>>>(SB, startv, deg, dinv, col, perm, Wt + 4 * 16384,
                                             conv_b + 3 * HID, ln_g + 3 * HID, ln_b + 3 * HID,
                                             SA, N, 2);

  // pooling + post MLP
  pool_post_kernel<<<NG, 128, 0, stream>>>(SA, batch, N, W_post, b_post, out, OUT_DIM);
}